// Round 10
// baseline (280.887 us; speedup 1.0000x reference)
//
#include <hip/hip_runtime.h>
#include <math.h>

// Problem constants
#define BATCH 4
#define CIN   256
#define CCH   128      // Cout
#define HW    4096     // 64*64
#define CQK   16

using short8   = __attribute__((ext_vector_type(8))) short;
using floatx4  = __attribute__((ext_vector_type(4))) float;
using floatx16 = __attribute__((ext_vector_type(16))) float;
using uint4v   = __attribute__((ext_vector_type(4))) unsigned int;

// tanh via raw intrinsics: 1 v_mul + v_exp + v_add + v_rcp + v_fma.
// Saturates correctly: x->+inf => exp2->inf => rcp->0 => 1; x->-inf => -1.
__device__ __forceinline__ float fast_tanh(float x) {
    float e = __builtin_amdgcn_exp2f(x * 2.8853900817779268f);  // e^{2x}
    float r = __builtin_amdgcn_rcpf(e + 1.0f);
    return __builtin_fmaf(-2.0f, r, 1.0f);
}

__device__ __forceinline__ unsigned short f2bf(float f) {
    unsigned u = __float_as_uint(f);
    u += 0x7fff + ((u >> 16) & 1);   // RNE
    return (unsigned short)(u >> 16);
}

__device__ __forceinline__ float bf2f(unsigned short u) {
    return __uint_as_float(((unsigned)u) << 16);
}

// C/D row map for mfma_f32_32x32x16: row = (r&3) + 8*(r>>2) + 4*hi, col = lane&31
#define ROWMAP(r, hi) (((r) & 3) + (((r) >> 2) << 3) + ((hi) << 2))

#define XTP_ROW   (66 * 256)          // shorts per padded row
#define XTP_BATCH (66 * 66 * 256)     // shorts per batch

// ---------------------------------------------------------------------------
// 1) prep_all: [0,1024) x-transpose+halo; [1024,2176) conv weights;
//    [2176,2256) qkv weights; [2256] zero stats. grid 2257, block 256.
// ---------------------------------------------------------------------------
__global__ __launch_bounds__(256) void prep_all_kernel(
        const float* __restrict__ x, const float* __restrict__ w,
        const float* __restrict__ qw, const float* __restrict__ qb,
        const float* __restrict__ kw, const float* __restrict__ kb,
        const float* __restrict__ vw, const float* __restrict__ vb,
        unsigned short* __restrict__ xTp, unsigned short* __restrict__ Wb2,
        unsigned short* __restrict__ Wqkv, float* __restrict__ biasAll,
        float* __restrict__ statsS, float* __restrict__ statsQ) {
    const int bx = blockIdx.x, tid = threadIdx.x;
    if (bx < 1024) {
        __shared__ unsigned short lds[64][72];
        const int ci0 = (bx & 3) << 6, yr = (bx >> 2) & 63, b = bx >> 8;
        const int cir = tid >> 2, xc = tid & 3;
        const float* xp = x + (((b << 8) + ci0 + cir) << 12) + (yr << 6) + xc * 16;
#pragma unroll
        for (int j = 0; j < 4; ++j) {
            float4 v = *(const float4*)(xp + j * 4);
            int xi = xc * 16 + j * 4;
            lds[xi + 0][cir] = f2bf(v.x);
            lds[xi + 1][cir] = f2bf(v.y);
            lds[xi + 2][cir] = f2bf(v.z);
            lds[xi + 3][cir] = f2bf(v.w);
        }
        const short8 z8 = (short8){0,0,0,0,0,0,0,0};
        if (tid < 16) {
            int col = (tid >> 3) ? 65 : 0;
            int part = tid & 7;
            *(short8*)(xTp + b * XTP_BATCH + (yr + 1) * XTP_ROW + col * 256 +
                       ci0 + part * 8) = z8;
        }
        if (yr == 0 || yr == 63) {
            int row = (yr == 0) ? 0 : 65;
            for (int e = tid; e < 528; e += 256) {
                int xi = e >> 3, part = e & 7;
                *(short8*)(xTp + b * XTP_BATCH + row * XTP_ROW + xi * 256 +
                           ci0 + part * 8) = z8;
            }
        }
        __syncthreads();
        const int xr = tid >> 2, part = tid & 3;
        unsigned short* dst = xTp + b * XTP_BATCH + (yr + 1) * XTP_ROW +
                              (xr + 1) * 256 + ci0 + part * 16;
        *(short8*)(dst + 0) = *(const short8*)&lds[xr][part * 16 + 0];
        *(short8*)(dst + 8) = *(const short8*)&lds[xr][part * 16 + 8];
    } else if (bx < 2176) {
        int o = (bx - 1024) * 256 + tid;                 // < 294912
        int s   = o & 31;
        int co  = (o >> 5) & 127;
        int cc  = (o >> 12) & 7;
        int tap = o >> 15;
        int ci  = (cc << 5) + s;
        Wb2[o] = f2bf(w[co * 2304 + ci * 9 + tap]);
    } else if (bx < 2256) {
        int idx = (bx - 2176) * 256 + tid;               // < 20480
        int o = idx >> 7, c = idx & 127;
        float wv = (o < 16) ? qw[(o << 7) + c]
                 : (o < 32) ? kw[((o - 16) << 7) + c]
                            : vw[((o - 32) << 7) + c];
        Wqkv[idx] = f2bf(wv);
        if (idx < 160)
            biasAll[idx] = (idx < 16) ? qb[idx] : (idx < 32) ? kb[idx - 16] : vb[idx - 32];
    } else {
        if (tid < 128) { statsS[tid] = 0.f; statsQ[tid] = 0.f; }
    }
}

// ---------------------------------------------------------------------------
// 2) Conv implicit GEMM + fused BN-stat partials. LDS-free, barrier-free.
//    Wave = 32 co x 32 px; block = 128 co x 32 px (x-half of one row).
//    cc-loop fully unrolled -> loads batched, latency hidden by ILP.
// grid(2, 64, 4) = 512 blocks -> 2 blocks/CU, block 256.
// ---------------------------------------------------------------------------
__global__ __launch_bounds__(256, 2) void conv_mfma_kernel(
        const unsigned short* __restrict__ xTp, const unsigned short* __restrict__ Wb2,
        float* __restrict__ y, float* __restrict__ statsS, float* __restrict__ statsQ) {
    const int tid = threadIdx.x;
    const int w = tid >> 6, lane = tid & 63, l15 = lane & 15, quad = lane >> 4;
    const int x0 = blockIdx.x << 5, yr = blockIdx.y, b = blockIdx.z;
    const int cobase = w << 5;

    floatx4 acc[2][2];
#pragma unroll
    for (int i = 0; i < 2; ++i)
#pragma unroll
        for (int j = 0; j < 2; ++j) acc[i][j] = (floatx4){0.f, 0.f, 0.f, 0.f};

    const unsigned short* xb = xTp + b * XTP_BATCH + yr * XTP_ROW;
    const int aco0 = cobase + l15;

#pragma unroll
    for (int ky = 0; ky < 3; ++ky) {
#pragma unroll
        for (int kx = 0; kx < 3; ++kx) {
            const unsigned short* arow = Wb2 + ((ky * 3 + kx) << 15);
            const unsigned short* brow = xb + ky * XTP_ROW + (x0 + kx) * 256;
#pragma unroll
            for (int cc = 0; cc < 8; ++cc) {
                short8 a0 = *(const short8*)(arow + (((cc << 7) + aco0) << 5) + quad * 8);
                short8 a1 = *(const short8*)(arow + (((cc << 7) + aco0 + 16) << 5) + quad * 8);
                short8 b0 = *(const short8*)(brow + (l15 << 8) + (cc << 5) + quad * 8);
                short8 b1 = *(const short8*)(brow + ((16 + l15) << 8) + (cc << 5) + quad * 8);
                acc[0][0] = __builtin_amdgcn_mfma_f32_16x16x32_bf16(a0, b0, acc[0][0], 0, 0, 0);
                acc[0][1] = __builtin_amdgcn_mfma_f32_16x16x32_bf16(a0, b1, acc[0][1], 0, 0, 0);
                acc[1][0] = __builtin_amdgcn_mfma_f32_16x16x32_bf16(a1, b0, acc[1][0], 0, 0, 0);
                acc[1][1] = __builtin_amdgcn_mfma_f32_16x16x32_bf16(a1, b1, acc[1][1], 0, 0, 0);
            }
        }
    }

    // stores
#pragma unroll
    for (int ms = 0; ms < 2; ++ms)
#pragma unroll
        for (int ns = 0; ns < 2; ++ns) {
            int px = x0 + (ns << 4) + l15;
#pragma unroll
            for (int r = 0; r < 4; ++r) {
                int co = cobase + ms * 16 + quad * 4 + r;
                y[(((b << 7) + co) << 12) + (yr << 6) + px] = acc[ms][ns][r];
            }
        }
    // fused BN stat partials: reduce over the 16 px lanes, add both n-frags
#pragma unroll
    for (int ms = 0; ms < 2; ++ms)
#pragma unroll
        for (int r = 0; r < 4; ++r) {
            float s = acc[ms][0][r] + acc[ms][1][r];
            float q = acc[ms][0][r] * acc[ms][0][r] + acc[ms][1][r] * acc[ms][1][r];
#pragma unroll
            for (int off = 1; off < 16; off <<= 1) {
                s += __shfl_xor(s, off);
                q += __shfl_xor(q, off);
            }
            if (l15 == 0) {
                int co = cobase + ms * 16 + quad * 4 + r;
                atomicAdd(&statsS[co], s);
                atomicAdd(&statsQ[co], q);
            }
        }
}

// ---------------------------------------------------------------------------
// 3) BN apply + ReLU (scale computed inline from sums) -> featB + fT.
// grid(2, 64, 4), block 256
// ---------------------------------------------------------------------------
__global__ __launch_bounds__(256) void bn_apply_kernel(
        const float* __restrict__ y, const float* __restrict__ statsS,
        const float* __restrict__ statsQ, const float* __restrict__ gamma,
        const float* __restrict__ beta, unsigned short* __restrict__ featB,
        unsigned short* __restrict__ fT) {
    __shared__ unsigned short lds[64][72];
    const int tid = threadIdx.x;
    const int c0 = blockIdx.x * 64, n0 = blockIdx.y * 64, b = blockIdx.z;
    const int cir = tid >> 2, xc = tid & 3;
    const int c = c0 + cir;
    const float S = statsS[c], Q = statsQ[c];
    const float mean = S * (1.f / 16384.f);
    const float var  = Q * (1.f / 16384.f) - mean * mean;
    const float rstd = rsqrtf(var + 1e-5f);
    const float sc = gamma[c] * rstd;
    const float sh = beta[c] - mean * sc;
    const float* yp = y + (((b << 7) + c) << 12) + n0 + xc * 16;
    unsigned short* fp = featB + (((b << 7) + c) << 12) + n0 + xc * 16;
#pragma unroll
    for (int j = 0; j < 4; ++j) {
        float4 v = *(const float4*)(yp + j * 4);
        ushort4 o;
        o.x = f2bf(fmaxf(fmaf(v.x, sc, sh), 0.f));
        o.y = f2bf(fmaxf(fmaf(v.y, sc, sh), 0.f));
        o.z = f2bf(fmaxf(fmaf(v.z, sc, sh), 0.f));
        o.w = f2bf(fmaxf(fmaf(v.w, sc, sh), 0.f));
        *(ushort4*)(fp + j * 4) = o;
        int ni = xc * 16 + j * 4;
        lds[ni + 0][cir] = o.x;
        lds[ni + 1][cir] = o.y;
        lds[ni + 2][cir] = o.z;
        lds[ni + 3][cir] = o.w;
    }
    __syncthreads();
    const int nr = tid >> 2, part = tid & 3;
    unsigned short* dst = fT + (((b << 12) + n0 + nr) << 7) + c0 + part * 16;
    *(short8*)(dst + 0) = *(const short8*)&lds[nr][part * 16 + 0];
    *(short8*)(dst + 8) = *(const short8*)&lds[nr][part * 16 + 8];
}

// ---------------------------------------------------------------------------
// 4) Fused cam_energy (blocks [0,256)) + qkv (blocks [256,512)). grid 512.
// ---------------------------------------------------------------------------
__global__ __launch_bounds__(256) void camqkv_kernel(
        const unsigned short* __restrict__ featB, float* __restrict__ ep,
        const unsigned short* __restrict__ Wqkv, const float* __restrict__ biasAll,
        const unsigned short* __restrict__ fT,
        unsigned short* __restrict__ qT, unsigned short* __restrict__ kT,
        unsigned short* __restrict__ vB) {
    const int bx = blockIdx.x, tid = threadIdx.x;
    const int l31 = tid & 31, hi = (tid >> 5) & 1;
    if (bx < 256) {
        // cam_energy: split-K 64, kc = bx&63, b = bx>>6
        const int kc = bx & 63, b = bx >> 6, wv = tid >> 6;
        floatx16 acc[4];
#pragma unroll
        for (int t = 0; t < 4; ++t)
#pragma unroll
            for (int r = 0; r < 16; ++r) acc[t][r] = 0.f;
        for (int s = 0; s < 4; ++s) {
            const int k0 = (kc << 6) + (s << 4) + (hi << 3);
            short8 fr = *(const short8*)&featB[(((b << 7) + (wv << 5) + l31) << 12) + k0];
            short8 fc0 = *(const short8*)&featB[(((b << 7) +  0 + l31) << 12) + k0];
            short8 fc1 = *(const short8*)&featB[(((b << 7) + 32 + l31) << 12) + k0];
            short8 fc2 = *(const short8*)&featB[(((b << 7) + 64 + l31) << 12) + k0];
            short8 fc3 = *(const short8*)&featB[(((b << 7) + 96 + l31) << 12) + k0];
            acc[0] = __builtin_amdgcn_mfma_f32_32x32x16_bf16(fr, fc0, acc[0], 0, 0, 0);
            acc[1] = __builtin_amdgcn_mfma_f32_32x32x16_bf16(fr, fc1, acc[1], 0, 0, 0);
            acc[2] = __builtin_amdgcn_mfma_f32_32x32x16_bf16(fr, fc2, acc[2], 0, 0, 0);
            acc[3] = __builtin_amdgcn_mfma_f32_32x32x16_bf16(fr, fc3, acc[3], 0, 0, 0);
        }
#pragma unroll
        for (int t = 0; t < 4; ++t)
#pragma unroll
            for (int r = 0; r < 16; ++r) {
                int c = ((tid >> 6) << 5) + ROWMAP(r, hi);
                int d = (t << 5) + l31;
                ep[(((kc << 2) + b) << 14) + (c << 7) + d] = acc[t][r];
            }
    } else {
        // qkv: bi = bx-256; ntile = bi&63, b = bi>>6
        const int bi = bx - 256, b = bi >> 6, w = tid >> 6;
        const int n0 = ((bi & 63) << 6) + ((w >> 1) << 5);
        const int tstart = (w & 1) ? 3 : 0;
        const int tcnt   = (w & 1) ? 2 : 3;
        floatx16 acc[3];
#pragma unroll
        for (int t = 0; t < 3; ++t)
#pragma unroll
            for (int r = 0; r < 16; ++r) acc[t][r] = 0.f;
        for (int s = 0; s < 8; ++s) {
            const int k0 = (s << 4) + (hi << 3);
            short8 bf = *(const short8*)&fT[(((b << 12) + n0 + l31) << 7) + k0];
#pragma unroll
            for (int ti = 0; ti < 3; ++ti) {
                if (ti < tcnt) {
                    short8 aw = *(const short8*)&Wqkv[((((tstart + ti) << 5) + l31) << 7) + k0];
                    acc[ti] = __builtin_amdgcn_mfma_f32_32x32x16_bf16(aw, bf, acc[ti], 0, 0, 0);
                }
            }
        }
        const int n = n0 + l31;
#pragma unroll
        for (int ti = 0; ti < 3; ++ti) {
            if (ti >= tcnt) continue;
            const int t = tstart + ti;
#pragma unroll
            for (int r = 0; r < 16; ++r) {
                int o = (t << 5) + ROWMAP(r, hi);
                float val = acc[ti][r] + biasAll[o];
                if (t == 0) {
                    if (o < 16) qT[(((b << 12) + n) << 4) + o] = f2bf(val);
                    else        kT[(((b << 12) + n) << 4) + o - 16] = f2bf(val);
                } else if (o >= 32) {
                    vB[(((b << 7) + o - 32) << 12) + n] = f2bf(val);
                }
            }
        }
    }
}

// ---------------------------------------------------------------------------
// 5) Fused pam (blocks [0,512)) + cam_attn (blocks [512,768)). grid 768.
//    pam: wave-autonomous, 4-way n-split, shfl hi-half swap, fast tanh.
// ---------------------------------------------------------------------------
__global__ __launch_bounds__(256) void pam_attn_kernel(
        const unsigned short* __restrict__ qT, const unsigned short* __restrict__ kT,
        const unsigned short* __restrict__ vB, unsigned short* __restrict__ pamP,
        const float* __restrict__ ep, unsigned short* __restrict__ attnB) {
    const int bx = blockIdx.x, tid = threadIdx.x;
    if (bx < 512) {
        const int nh = bx & 3, b = bx >> 7;
        const int w = tid >> 6, lane = tid & 63, l31 = lane & 31, hi = lane >> 5;
        const int m0 = (((bx >> 2) & 31) << 7) + (w << 5);

        short8 bq = *(const short8*)&qT[(((b << 12) + m0 + l31) << 4) + hi * 8];

        floatx16 acc[4], zero16;
#pragma unroll
        for (int r = 0; r < 16; ++r) {
            acc[0][r] = 0.f; acc[1][r] = 0.f; acc[2][r] = 0.f; acc[3][r] = 0.f;
            zero16[r] = 0.f;
        }

        const int nbase = nh << 10;
        short8 ak = *(const short8*)&kT[(((b << 12) + nbase + l31) << 4) + hi * 8];

        for (int nc = 0; nc < 32; ++nc) {
            const int na = nbase + (nc << 5);
            short8 av[8];
#pragma unroll
            for (int ct = 0; ct < 4; ++ct) {
                const unsigned short* vp = vB + (((b << 7) + (ct << 5) + l31) << 12) + na + hi * 8;
                av[2 * ct]     = *(const short8*)(vp);
                av[2 * ct + 1] = *(const short8*)(vp + 16);
            }
            floatx16 s = __builtin_amdgcn_mfma_f32_32x32x16_bf16(ak, bq, zero16, 0, 0, 0);
            if (nc < 31)
                ak = *(const short8*)&kT[(((b << 12) + na + 32 + l31) << 4) + hi * 8];
            unsigned p[8];
#pragma unroll
            for (int i = 0; i < 8; ++i) {
                float t0 = fast_tanh(s[2 * i]);
                float t1 = fast_tanh(s[2 * i + 1]);
                p[i] = (__float_as_uint(t1) & 0xFFFF0000u) | (__float_as_uint(t0) >> 16);
            }
            unsigned sh[8];
#pragma unroll
            for (int i = 0; i < 8; ++i) sh[i] = __shfl_xor(p[i], 32, 64);
            uint4v b1u, b2u;
            b1u[0] = hi ? sh[2] : p[0];
            b1u[1] = hi ? sh[3] : p[1];
            b1u[2] = hi ? p[2] : sh[0];
            b1u[3] = hi ? p[3] : sh[1];
            b2u[0] = hi ? sh[6] : p[4];
            b2u[1] = hi ? sh[7] : p[5];
            b2u[2] = hi ? p[6] : sh[4];
            b2u[3] = hi ? p[7] : sh[5];
            short8 B1 = __builtin_bit_cast(short8, b1u);
            short8 B2 = __builtin_bit_cast(short8, b2u);
#pragma unroll
            for (int ct = 0; ct < 4; ++ct) {
                acc[ct] = __builtin_amdgcn_mfma_f32_32x32x16_bf16(av[2 * ct], B1, acc[ct], 0, 0, 0);
                acc[ct] = __builtin_amdgcn_mfma_f32_32x32x16_bf16(av[2 * ct + 1], B2, acc[ct], 0, 0, 0);
            }
        }
        const int pbase = (((nh << 2) + b) << 19) + m0 + l31;
#pragma unroll
        for (int ct = 0; ct < 4; ++ct)
#pragma unroll
            for (int r = 0; r < 16; ++r) {
                int c = (ct << 5) + ROWMAP(r, hi);
                pamP[pbase + (c << 12)] = f2bf(acc[ct][r]);
            }
    } else {
        // cam_attn: bi = bx-512 (0..255): b = bi>>6, 2 rows per block
        const int bi = bx - 512, b = bi >> 6;
        const int half = tid >> 7, t = tid & 127;
        const int c = ((bi & 63) << 1) + half;
        float v = 0.f;
#pragma unroll 8
        for (int s = 0; s < 64; ++s)
            v += ep[(((s << 2) + b) << 14) + (c << 7) + t];
        float m = v;
        for (int off = 32; off; off >>= 1) m = fmaxf(m, __shfl_down(m, off));
        __shared__ float mx[4];
        if ((tid & 63) == 0) mx[tid >> 6] = m;
        __syncthreads();
        float M = fmaxf(mx[half << 1], mx[(half << 1) + 1]);
        attnB[(b << 14) + (c << 7) + t] = f2bf(fast_tanh(M - v));
    }
}

// ---------------------------------------------------------------------------
// 6) Combine: out = 3*feat + g_ca*(attn @ f) + g_pa*(sum_4 pamP).
// grid(64, 4), block 256.
// ---------------------------------------------------------------------------
__global__ __launch_bounds__(256) void combine_kernel(
        const unsigned short* __restrict__ attnB, const unsigned short* __restrict__ fT,
        const unsigned short* __restrict__ featB, const unsigned short* __restrict__ pamP,
        const float* __restrict__ gca, const float* __restrict__ gpa,
        float* __restrict__ out) {
    const int b = blockIdx.y, tid = threadIdx.x;
    const int w = tid >> 6, l31 = tid & 31, hi = (tid >> 5) & 1;
    const int m0 = (blockIdx.x << 6) + ((w >> 1) << 5);
    const int ct0 = (w & 1) << 1;
    floatx16 acc[2];
#pragma unroll
    for (int t = 0; t < 2; ++t)
#pragma unroll
        for (int r = 0; r < 16; ++r) acc[t][r] = 0.f;

    for (int s = 0; s < 8; ++s) {
        const int k0 = (s << 4) + (hi << 3);
        short8 bf = *(const short8*)&fT[(((b << 12) + m0 + l31) << 7) + k0];
        short8 a0 = *(const short8*)&attnB[(b << 14) + ((((ct0 + 0) << 5) + l31) << 7) + k0];
        short8 a1 = *(const short8*)&attnB[(b << 14) + ((((ct0 + 1) << 5) + l31) << 7) + k0];
        acc[0] = __builtin_amdgcn_mfma_f32_32x32x16_bf16(a0, bf, acc[0], 0, 0, 0);
        acc[1] = __builtin_amdgcn_mfma_f32_32x32x16_bf16(a1, bf, acc[1], 0, 0, 0);
    }
    const float gc = gca[0], gp = gpa[0];
    const int m = m0 + l31;
#pragma unroll
    for (int t = 0; t < 2; ++t)
#pragma unroll
        for (int r = 0; r < 16; ++r) {
            int c = ((ct0 + t) << 5) + ROWMAP(r, hi);
            int ci = (c << 12) + m;
            float p = bf2f(pamP[((0 * 4 + b) << 19) + ci]) +
                      bf2f(pamP[((1 * 4 + b) << 19) + ci]) +
                      bf2f(pamP[((2 * 4 + b) << 19) + ci]) +
                      bf2f(pamP[((3 * 4 + b) << 19) + ci]);
            float fb = bf2f(featB[(((b << 7) + c) << 12) + m]);
            out[(((b << 7) + c) << 12) + m] = 3.f * fb + gc * acc[t][r] + gp * p;
        }
}

// ---------------------------------------------------------------------------
extern "C" void kernel_launch(void* const* d_in, const int* in_sizes, int n_in,
                              void* d_out, int out_size, void* d_ws, size_t ws_size,
                              hipStream_t stream) {
    const float* x      = (const float*)d_in[0];
    const float* conv_w = (const float*)d_in[1];
    const float* bn_g   = (const float*)d_in[2];
    const float* bn_b   = (const float*)d_in[3];
    const float* q_w    = (const float*)d_in[4];
    const float* q_b    = (const float*)d_in[5];
    const float* k_w    = (const float*)d_in[6];
    const float* k_b    = (const float*)d_in[7];
    const float* v_w    = (const float*)d_in[8];
    const float* v_b    = (const float*)d_in[9];
    const float* gca    = (const float*)d_in[10];
    const float* gpa    = (const float*)d_in[11];
    float* out = (float*)d_out;

    float* ws = (float*)d_ws;
    // dead-by-pam region (aliased by pamP, 4 slices = 4,194,304 f):
    float* convY  = ws;                                      // 2,097,152 f
    unsigned short* xTp = (unsigned short*)(ws + 2097152);   // 2,230,272 f
    // alive-through-pam region:
    float* ep     = ws + 4327424;                            // 4,194,304 f (64 slices)
    unsigned short* Wb2  = (unsigned short*)(ws + 8521728);  // 147,456 f
    unsigned short* Wqkv = (unsigned short*)(ws + 8669184);  // 10,240 f
    float* statsS  = ws + 8679424;                           // 128
    float* statsQ  = ws + 8679552;                           // 128
    float* biasAll = ws + 8679680;                           // 192 (pad)
    unsigned short* attnB = (unsigned short*)(ws + 8679872);  // 32,768 f
    unsigned short* qT    = (unsigned short*)(ws + 8712640);  // 131,072 f
    unsigned short* kT    = (unsigned short*)(ws + 8843712);  // 131,072 f
    unsigned short* vB    = (unsigned short*)(ws + 8974784);  // 1,048,576 f
    unsigned short* featB = (unsigned short*)(ws + 10023360); // 1,048,576 f
    unsigned short* fT    = (unsigned short*)(ws + 11071936); // 1,048,576 f -> 12,120,512 f
    // pamP bf16[4][4][128][4096] = 8,388,608 sh = 4,194,304 f, aliases
    // [0, 4,327,424) = convY+xTp (dead before pam; ep stays clear).
    unsigned short* pamP  = (unsigned short*)ws;

    prep_all_kernel<<<2257, 256, 0, stream>>>(x, conv_w, q_w, q_b, k_w, k_b,
                                              v_w, v_b, xTp, Wb2, Wqkv, biasAll,
                                              statsS, statsQ);
    conv_mfma_kernel<<<dim3(2, 64, 4), 256, 0, stream>>>(xTp, Wb2, convY, statsS, statsQ);
    bn_apply_kernel<<<dim3(2, 64, 4), 256, 0, stream>>>(convY, statsS, statsQ,
                                                        bn_g, bn_b, featB, fT);
    camqkv_kernel<<<512, 256, 0, stream>>>(featB, ep, Wqkv, biasAll, fT, qT, kT, vB);
    pam_attn_kernel<<<768, 256, 0, stream>>>(qT, kT, vB, pamP, ep, attnB);
    combine_kernel<<<dim3(64, 4), 256, 0, stream>>>(attnB, fT, featB, pamP, gca, gpa, out);
}

// Round 11
// 280.522 us; speedup vs baseline: 1.0013x; 1.0013x over previous
//
#include <hip/hip_runtime.h>
#include <math.h>

// Problem constants
#define BATCH 4
#define CIN   256
#define CCH   128      // Cout
#define HW    4096     // 64*64
#define CQK   16

using short8   = __attribute__((ext_vector_type(8))) short;
using floatx4  = __attribute__((ext_vector_type(4))) float;
using floatx16 = __attribute__((ext_vector_type(16))) float;
using uint4v   = __attribute__((ext_vector_type(4))) unsigned int;

// tanh via raw intrinsics: 1 v_mul + v_exp + v_add + v_rcp + v_fma.
// Saturates correctly: x->+inf => exp2->inf => rcp->0 => 1; x->-inf => -1.
__device__ __forceinline__ float fast_tanh(float x) {
    float e = __builtin_amdgcn_exp2f(x * 2.8853900817779268f);  // e^{2x}
    float r = __builtin_amdgcn_rcpf(e + 1.0f);
    return __builtin_fmaf(-2.0f, r, 1.0f);
}

__device__ __forceinline__ unsigned short f2bf(float f) {
    unsigned u = __float_as_uint(f);
    u += 0x7fff + ((u >> 16) & 1);   // RNE
    return (unsigned short)(u >> 16);
}

__device__ __forceinline__ float bf2f(unsigned short u) {
    return __uint_as_float(((unsigned)u) << 16);
}

// C/D row map for mfma_f32_32x32x16: row = (r&3) + 8*(r>>2) + 4*hi, col = lane&31
#define ROWMAP(r, hi) (((r) & 3) + (((r) >> 2) << 3) + ((hi) << 2))

#define XTP_ROW   (66 * 256)          // shorts per padded row
#define XTP_BATCH (66 * 66 * 256)     // shorts per batch

// ---------------------------------------------------------------------------
// 1) prep_all: [0,1024) x-transpose+halo; [1024,2176) conv weights;
//    [2176,2256) qkv weights; [2256] zero stats. grid 2257, block 256.
// ---------------------------------------------------------------------------
__global__ __launch_bounds__(256) void prep_all_kernel(
        const float* __restrict__ x, const float* __restrict__ w,
        const float* __restrict__ qw, const float* __restrict__ qb,
        const float* __restrict__ kw, const float* __restrict__ kb,
        const float* __restrict__ vw, const float* __restrict__ vb,
        unsigned short* __restrict__ xTp, unsigned short* __restrict__ Wb2,
        unsigned short* __restrict__ Wqkv, float* __restrict__ biasAll,
        float* __restrict__ statsS, float* __restrict__ statsQ) {
    const int bx = blockIdx.x, tid = threadIdx.x;
    if (bx < 1024) {
        __shared__ unsigned short lds[64][72];
        const int ci0 = (bx & 3) << 6, yr = (bx >> 2) & 63, b = bx >> 8;
        const int cir = tid >> 2, xc = tid & 3;
        const float* xp = x + (((b << 8) + ci0 + cir) << 12) + (yr << 6) + xc * 16;
#pragma unroll
        for (int j = 0; j < 4; ++j) {
            float4 v = *(const float4*)(xp + j * 4);
            int xi = xc * 16 + j * 4;
            lds[xi + 0][cir] = f2bf(v.x);
            lds[xi + 1][cir] = f2bf(v.y);
            lds[xi + 2][cir] = f2bf(v.z);
            lds[xi + 3][cir] = f2bf(v.w);
        }
        const short8 z8 = (short8){0,0,0,0,0,0,0,0};
        if (tid < 16) {
            int col = (tid >> 3) ? 65 : 0;
            int part = tid & 7;
            *(short8*)(xTp + b * XTP_BATCH + (yr + 1) * XTP_ROW + col * 256 +
                       ci0 + part * 8) = z8;
        }
        if (yr == 0 || yr == 63) {
            int row = (yr == 0) ? 0 : 65;
            for (int e = tid; e < 528; e += 256) {
                int xi = e >> 3, part = e & 7;
                *(short8*)(xTp + b * XTP_BATCH + row * XTP_ROW + xi * 256 +
                           ci0 + part * 8) = z8;
            }
        }
        __syncthreads();
        const int xr = tid >> 2, part = tid & 3;
        unsigned short* dst = xTp + b * XTP_BATCH + (yr + 1) * XTP_ROW +
                              (xr + 1) * 256 + ci0 + part * 16;
        *(short8*)(dst + 0) = *(const short8*)&lds[xr][part * 16 + 0];
        *(short8*)(dst + 8) = *(const short8*)&lds[xr][part * 16 + 8];
    } else if (bx < 2176) {
        int o = (bx - 1024) * 256 + tid;                 // < 294912
        int s   = o & 31;
        int co  = (o >> 5) & 127;
        int cc  = (o >> 12) & 7;
        int tap = o >> 15;
        int ci  = (cc << 5) + s;
        Wb2[o] = f2bf(w[co * 2304 + ci * 9 + tap]);
    } else if (bx < 2256) {
        int idx = (bx - 2176) * 256 + tid;               // < 20480
        int o = idx >> 7, c = idx & 127;
        float wv = (o < 16) ? qw[(o << 7) + c]
                 : (o < 32) ? kw[((o - 16) << 7) + c]
                            : vw[((o - 32) << 7) + c];
        Wqkv[idx] = f2bf(wv);
        if (idx < 160)
            biasAll[idx] = (idx < 16) ? qb[idx] : (idx < 32) ? kb[idx - 16] : vb[idx - 32];
    } else {
        if (tid < 128) { statsS[tid] = 0.f; statsQ[tid] = 0.f; }
    }
}

// ---------------------------------------------------------------------------
// 2) Conv implicit GEMM + fused BN-stat partials. LDS-free, barrier-free.
//    Wave = 32 co x 32 px. Per tap: ALL 32 fragment loads issued into
//    register arrays (explicit MLP — the compiler reuses 4 dest regs if we
//    interleave, serializing on memory latency; R10 post-mortem), then 32
//    MFMAs consume them.
// grid(2, 64, 4) = 512 blocks -> 2 blocks/CU, block 256.
// ---------------------------------------------------------------------------
__global__ __launch_bounds__(256) void conv_mfma_kernel(
        const unsigned short* __restrict__ xTp, const unsigned short* __restrict__ Wb2,
        float* __restrict__ y, float* __restrict__ statsS, float* __restrict__ statsQ) {
    const int tid = threadIdx.x;
    const int w = tid >> 6, lane = tid & 63, l15 = lane & 15, quad = lane >> 4;
    const int x0 = blockIdx.x << 5, yr = blockIdx.y, b = blockIdx.z;
    const int cobase = w << 5;

    floatx4 acc[2][2];
#pragma unroll
    for (int i = 0; i < 2; ++i)
#pragma unroll
        for (int j = 0; j < 2; ++j) acc[i][j] = (floatx4){0.f, 0.f, 0.f, 0.f};

    const unsigned short* xb = xTp + b * XTP_BATCH + yr * XTP_ROW;
    const int aco0 = cobase + l15;

#pragma unroll
    for (int ky = 0; ky < 3; ++ky) {
#pragma unroll
        for (int kx = 0; kx < 3; ++kx) {
            const unsigned short* arow = Wb2 + ((ky * 3 + kx) << 15);
            const unsigned short* brow = xb + ky * XTP_ROW + (x0 + kx) * 256;
            short8 A0[8], A1[8], B0[8], B1[8];
#pragma unroll
            for (int cc = 0; cc < 8; ++cc) {
                B0[cc] = *(const short8*)(brow + (l15 << 8) + (cc << 5) + quad * 8);
                B1[cc] = *(const short8*)(brow + ((16 + l15) << 8) + (cc << 5) + quad * 8);
            }
#pragma unroll
            for (int cc = 0; cc < 8; ++cc) {
                A0[cc] = *(const short8*)(arow + (((cc << 7) + aco0) << 5) + quad * 8);
                A1[cc] = *(const short8*)(arow + (((cc << 7) + aco0 + 16) << 5) + quad * 8);
            }
#pragma unroll
            for (int cc = 0; cc < 8; ++cc) {
                acc[0][0] = __builtin_amdgcn_mfma_f32_16x16x32_bf16(A0[cc], B0[cc], acc[0][0], 0, 0, 0);
                acc[0][1] = __builtin_amdgcn_mfma_f32_16x16x32_bf16(A0[cc], B1[cc], acc[0][1], 0, 0, 0);
                acc[1][0] = __builtin_amdgcn_mfma_f32_16x16x32_bf16(A1[cc], B0[cc], acc[1][0], 0, 0, 0);
                acc[1][1] = __builtin_amdgcn_mfma_f32_16x16x32_bf16(A1[cc], B1[cc], acc[1][1], 0, 0, 0);
            }
        }
    }

    // stores
#pragma unroll
    for (int ms = 0; ms < 2; ++ms)
#pragma unroll
        for (int ns = 0; ns < 2; ++ns) {
            int px = x0 + (ns << 4) + l15;
#pragma unroll
            for (int r = 0; r < 4; ++r) {
                int co = cobase + ms * 16 + quad * 4 + r;
                y[(((b << 7) + co) << 12) + (yr << 6) + px] = acc[ms][ns][r];
            }
        }
    // fused BN stat partials: reduce over the 16 px lanes, add both n-frags
#pragma unroll
    for (int ms = 0; ms < 2; ++ms)
#pragma unroll
        for (int r = 0; r < 4; ++r) {
            float s = acc[ms][0][r] + acc[ms][1][r];
            float q = acc[ms][0][r] * acc[ms][0][r] + acc[ms][1][r] * acc[ms][1][r];
#pragma unroll
            for (int off = 1; off < 16; off <<= 1) {
                s += __shfl_xor(s, off);
                q += __shfl_xor(q, off);
            }
            if (l15 == 0) {
                int co = cobase + ms * 16 + quad * 4 + r;
                atomicAdd(&statsS[co], s);
                atomicAdd(&statsQ[co], q);
            }
        }
}

// ---------------------------------------------------------------------------
// 3) BN apply + ReLU (scale computed inline from sums) -> featB + fT.
// grid(2, 64, 4), block 256
// ---------------------------------------------------------------------------
__global__ __launch_bounds__(256) void bn_apply_kernel(
        const float* __restrict__ y, const float* __restrict__ statsS,
        const float* __restrict__ statsQ, const float* __restrict__ gamma,
        const float* __restrict__ beta, unsigned short* __restrict__ featB,
        unsigned short* __restrict__ fT) {
    __shared__ unsigned short lds[64][72];
    const int tid = threadIdx.x;
    const int c0 = blockIdx.x * 64, n0 = blockIdx.y * 64, b = blockIdx.z;
    const int cir = tid >> 2, xc = tid & 3;
    const int c = c0 + cir;
    const float S = statsS[c], Q = statsQ[c];
    const float mean = S * (1.f / 16384.f);
    const float var  = Q * (1.f / 16384.f) - mean * mean;
    const float rstd = rsqrtf(var + 1e-5f);
    const float sc = gamma[c] * rstd;
    const float sh = beta[c] - mean * sc;
    const float* yp = y + (((b << 7) + c) << 12) + n0 + xc * 16;
    unsigned short* fp = featB + (((b << 7) + c) << 12) + n0 + xc * 16;
#pragma unroll
    for (int j = 0; j < 4; ++j) {
        float4 v = *(const float4*)(yp + j * 4);
        ushort4 o;
        o.x = f2bf(fmaxf(fmaf(v.x, sc, sh), 0.f));
        o.y = f2bf(fmaxf(fmaf(v.y, sc, sh), 0.f));
        o.z = f2bf(fmaxf(fmaf(v.z, sc, sh), 0.f));
        o.w = f2bf(fmaxf(fmaf(v.w, sc, sh), 0.f));
        *(ushort4*)(fp + j * 4) = o;
        int ni = xc * 16 + j * 4;
        lds[ni + 0][cir] = o.x;
        lds[ni + 1][cir] = o.y;
        lds[ni + 2][cir] = o.z;
        lds[ni + 3][cir] = o.w;
    }
    __syncthreads();
    const int nr = tid >> 2, part = tid & 3;
    unsigned short* dst = fT + (((b << 12) + n0 + nr) << 7) + c0 + part * 16;
    *(short8*)(dst + 0) = *(const short8*)&lds[nr][part * 16 + 0];
    *(short8*)(dst + 8) = *(const short8*)&lds[nr][part * 16 + 8];
}

// ---------------------------------------------------------------------------
// 4) Fused cam_energy (blocks [0,256)) + qkv (blocks [256,512)). grid 512.
// ---------------------------------------------------------------------------
__global__ __launch_bounds__(256) void camqkv_kernel(
        const unsigned short* __restrict__ featB, float* __restrict__ ep,
        const unsigned short* __restrict__ Wqkv, const float* __restrict__ biasAll,
        const unsigned short* __restrict__ fT,
        unsigned short* __restrict__ qT, unsigned short* __restrict__ kT,
        unsigned short* __restrict__ vB) {
    const int bx = blockIdx.x, tid = threadIdx.x;
    const int l31 = tid & 31, hi = (tid >> 5) & 1;
    if (bx < 256) {
        // cam_energy: split-K 64, kc = bx&63, b = bx>>6
        const int kc = bx & 63, b = bx >> 6, wv = tid >> 6;
        floatx16 acc[4];
#pragma unroll
        for (int t = 0; t < 4; ++t)
#pragma unroll
            for (int r = 0; r < 16; ++r) acc[t][r] = 0.f;
        for (int s = 0; s < 4; ++s) {
            const int k0 = (kc << 6) + (s << 4) + (hi << 3);
            short8 fr = *(const short8*)&featB[(((b << 7) + (wv << 5) + l31) << 12) + k0];
            short8 fc0 = *(const short8*)&featB[(((b << 7) +  0 + l31) << 12) + k0];
            short8 fc1 = *(const short8*)&featB[(((b << 7) + 32 + l31) << 12) + k0];
            short8 fc2 = *(const short8*)&featB[(((b << 7) + 64 + l31) << 12) + k0];
            short8 fc3 = *(const short8*)&featB[(((b << 7) + 96 + l31) << 12) + k0];
            acc[0] = __builtin_amdgcn_mfma_f32_32x32x16_bf16(fr, fc0, acc[0], 0, 0, 0);
            acc[1] = __builtin_amdgcn_mfma_f32_32x32x16_bf16(fr, fc1, acc[1], 0, 0, 0);
            acc[2] = __builtin_amdgcn_mfma_f32_32x32x16_bf16(fr, fc2, acc[2], 0, 0, 0);
            acc[3] = __builtin_amdgcn_mfma_f32_32x32x16_bf16(fr, fc3, acc[3], 0, 0, 0);
        }
#pragma unroll
        for (int t = 0; t < 4; ++t)
#pragma unroll
            for (int r = 0; r < 16; ++r) {
                int c = ((tid >> 6) << 5) + ROWMAP(r, hi);
                int d = (t << 5) + l31;
                ep[(((kc << 2) + b) << 14) + (c << 7) + d] = acc[t][r];
            }
    } else {
        // qkv: bi = bx-256; ntile = bi&63, b = bi>>6
        const int bi = bx - 256, b = bi >> 6, w = tid >> 6;
        const int n0 = ((bi & 63) << 6) + ((w >> 1) << 5);
        const int tstart = (w & 1) ? 3 : 0;
        const int tcnt   = (w & 1) ? 2 : 3;
        floatx16 acc[3];
#pragma unroll
        for (int t = 0; t < 3; ++t)
#pragma unroll
            for (int r = 0; r < 16; ++r) acc[t][r] = 0.f;
        for (int s = 0; s < 8; ++s) {
            const int k0 = (s << 4) + (hi << 3);
            short8 bf = *(const short8*)&fT[(((b << 12) + n0 + l31) << 7) + k0];
#pragma unroll
            for (int ti = 0; ti < 3; ++ti) {
                if (ti < tcnt) {
                    short8 aw = *(const short8*)&Wqkv[((((tstart + ti) << 5) + l31) << 7) + k0];
                    acc[ti] = __builtin_amdgcn_mfma_f32_32x32x16_bf16(aw, bf, acc[ti], 0, 0, 0);
                }
            }
        }
        const int n = n0 + l31;
#pragma unroll
        for (int ti = 0; ti < 3; ++ti) {
            if (ti >= tcnt) continue;
            const int t = tstart + ti;
#pragma unroll
            for (int r = 0; r < 16; ++r) {
                int o = (t << 5) + ROWMAP(r, hi);
                float val = acc[ti][r] + biasAll[o];
                if (t == 0) {
                    if (o < 16) qT[(((b << 12) + n) << 4) + o] = f2bf(val);
                    else        kT[(((b << 12) + n) << 4) + o - 16] = f2bf(val);
                } else if (o >= 32) {
                    vB[(((b << 7) + o - 32) << 12) + n] = f2bf(val);
                }
            }
        }
    }
}

// ---------------------------------------------------------------------------
// 5) Fused pam (blocks [0,512)) + cam_attn (blocks [512,768)). grid 768.
//    pam: wave-autonomous, 4-way n-split, shfl hi-half swap, fast tanh.
// ---------------------------------------------------------------------------
__global__ __launch_bounds__(256) void pam_attn_kernel(
        const unsigned short* __restrict__ qT, const unsigned short* __restrict__ kT,
        const unsigned short* __restrict__ vB, unsigned short* __restrict__ pamP,
        const float* __restrict__ ep, unsigned short* __restrict__ attnB) {
    const int bx = blockIdx.x, tid = threadIdx.x;
    if (bx < 512) {
        const int nh = bx & 3, b = bx >> 7;
        const int w = tid >> 6, lane = tid & 63, l31 = lane & 31, hi = lane >> 5;
        const int m0 = (((bx >> 2) & 31) << 7) + (w << 5);

        short8 bq = *(const short8*)&qT[(((b << 12) + m0 + l31) << 4) + hi * 8];

        floatx16 acc[4], zero16;
#pragma unroll
        for (int r = 0; r < 16; ++r) {
            acc[0][r] = 0.f; acc[1][r] = 0.f; acc[2][r] = 0.f; acc[3][r] = 0.f;
            zero16[r] = 0.f;
        }

        const int nbase = nh << 10;
        short8 ak = *(const short8*)&kT[(((b << 12) + nbase + l31) << 4) + hi * 8];

        for (int nc = 0; nc < 32; ++nc) {
            const int na = nbase + (nc << 5);
            short8 av[8];
#pragma unroll
            for (int ct = 0; ct < 4; ++ct) {
                const unsigned short* vp = vB + (((b << 7) + (ct << 5) + l31) << 12) + na + hi * 8;
                av[2 * ct]     = *(const short8*)(vp);
                av[2 * ct + 1] = *(const short8*)(vp + 16);
            }
            floatx16 s = __builtin_amdgcn_mfma_f32_32x32x16_bf16(ak, bq, zero16, 0, 0, 0);
            if (nc < 31)
                ak = *(const short8*)&kT[(((b << 12) + na + 32 + l31) << 4) + hi * 8];
            unsigned p[8];
#pragma unroll
            for (int i = 0; i < 8; ++i) {
                float t0 = fast_tanh(s[2 * i]);
                float t1 = fast_tanh(s[2 * i + 1]);
                p[i] = (__float_as_uint(t1) & 0xFFFF0000u) | (__float_as_uint(t0) >> 16);
            }
            unsigned sh[8];
#pragma unroll
            for (int i = 0; i < 8; ++i) sh[i] = __shfl_xor(p[i], 32, 64);
            uint4v b1u, b2u;
            b1u[0] = hi ? sh[2] : p[0];
            b1u[1] = hi ? sh[3] : p[1];
            b1u[2] = hi ? p[2] : sh[0];
            b1u[3] = hi ? p[3] : sh[1];
            b2u[0] = hi ? sh[6] : p[4];
            b2u[1] = hi ? sh[7] : p[5];
            b2u[2] = hi ? p[6] : sh[4];
            b2u[3] = hi ? p[7] : sh[5];
            short8 B1 = __builtin_bit_cast(short8, b1u);
            short8 B2 = __builtin_bit_cast(short8, b2u);
#pragma unroll
            for (int ct = 0; ct < 4; ++ct) {
                acc[ct] = __builtin_amdgcn_mfma_f32_32x32x16_bf16(av[2 * ct], B1, acc[ct], 0, 0, 0);
                acc[ct] = __builtin_amdgcn_mfma_f32_32x32x16_bf16(av[2 * ct + 1], B2, acc[ct], 0, 0, 0);
            }
        }
        const int pbase = (((nh << 2) + b) << 19) + m0 + l31;
#pragma unroll
        for (int ct = 0; ct < 4; ++ct)
#pragma unroll
            for (int r = 0; r < 16; ++r) {
                int c = (ct << 5) + ROWMAP(r, hi);
                pamP[pbase + (c << 12)] = f2bf(acc[ct][r]);
            }
    } else {
        // cam_attn: bi = bx-512 (0..255): b = bi>>6, 2 rows per block
        const int bi = bx - 512, b = bi >> 6;
        const int half = tid >> 7, t = tid & 127;
        const int c = ((bi & 63) << 1) + half;
        float v = 0.f;
#pragma unroll 8
        for (int s = 0; s < 64; ++s)
            v += ep[(((s << 2) + b) << 14) + (c << 7) + t];
        float m = v;
        for (int off = 32; off; off >>= 1) m = fmaxf(m, __shfl_down(m, off));
        __shared__ float mx[4];
        if ((tid & 63) == 0) mx[tid >> 6] = m;
        __syncthreads();
        float M = fmaxf(mx[half << 1], mx[(half << 1) + 1]);
        attnB[(b << 14) + (c << 7) + t] = f2bf(fast_tanh(M - v));
    }
}

// ---------------------------------------------------------------------------
// 6) Combine: out = 3*feat + g_ca*(attn @ f) + g_pa*(sum_4 pamP).
// grid(64, 4), block 256.
// ---------------------------------------------------------------------------
__global__ __launch_bounds__(256) void combine_kernel(
        const unsigned short* __restrict__ attnB, const unsigned short* __restrict__ fT,
        const unsigned short* __restrict__ featB, const unsigned short* __restrict__ pamP,
        const float* __restrict__ gca, const float* __restrict__ gpa,
        float* __restrict__ out) {
    const int b = blockIdx.y, tid = threadIdx.x;
    const int w = tid >> 6, l31 = tid & 31, hi = (tid >> 5) & 1;
    const int m0 = (blockIdx.x << 6) + ((w >> 1) << 5);
    const int ct0 = (w & 1) << 1;
    floatx16 acc[2];
#pragma unroll
    for (int t = 0; t < 2; ++t)
#pragma unroll
        for (int r = 0; r < 16; ++r) acc[t][r] = 0.f;

    for (int s = 0; s < 8; ++s) {
        const int k0 = (s << 4) + (hi << 3);
        short8 bf = *(const short8*)&fT[(((b << 12) + m0 + l31) << 7) + k0];
        short8 a0 = *(const short8*)&attnB[(b << 14) + ((((ct0 + 0) << 5) + l31) << 7) + k0];
        short8 a1 = *(const short8*)&attnB[(b << 14) + ((((ct0 + 1) << 5) + l31) << 7) + k0];
        acc[0] = __builtin_amdgcn_mfma_f32_32x32x16_bf16(a0, bf, acc[0], 0, 0, 0);
        acc[1] = __builtin_amdgcn_mfma_f32_32x32x16_bf16(a1, bf, acc[1], 0, 0, 0);
    }
    const float gc = gca[0], gp = gpa[0];
    const int m = m0 + l31;
#pragma unroll
    for (int t = 0; t < 2; ++t)
#pragma unroll
        for (int r = 0; r < 16; ++r) {
            int c = ((ct0 + t) << 5) + ROWMAP(r, hi);
            int ci = (c << 12) + m;
            float p = bf2f(pamP[((0 * 4 + b) << 19) + ci]) +
                      bf2f(pamP[((1 * 4 + b) << 19) + ci]) +
                      bf2f(pamP[((2 * 4 + b) << 19) + ci]) +
                      bf2f(pamP[((3 * 4 + b) << 19) + ci]);
            float fb = bf2f(featB[(((b << 7) + c) << 12) + m]);
            out[(((b << 7) + c) << 12) + m] = 3.f * fb + gc * acc[t][r] + gp * p;
        }
}

// ---------------------------------------------------------------------------
extern "C" void kernel_launch(void* const* d_in, const int* in_sizes, int n_in,
                              void* d_out, int out_size, void* d_ws, size_t ws_size,
                              hipStream_t stream) {
    const float* x      = (const float*)d_in[0];
    const float* conv_w = (const float*)d_in[1];
    const float* bn_g   = (const float*)d_in[2];
    const float* bn_b   = (const float*)d_in[3];
    const float* q_w    = (const float*)d_in[4];
    const float* q_b    = (const float*)d_in[5];
    const float* k_w    = (const float*)d_in[6];
    const float* k_b    = (const float*)d_in[7];
    const float* v_w    = (const float*)d_in[8];
    const float* v_b    = (const float*)d_in[9];
    const float* gca    = (const float*)d_in[10];
    const float* gpa    = (const float*)d_in[11];
    float* out = (float*)d_out;

    float* ws = (float*)d_ws;
    // dead-by-pam region (aliased by pamP, 4 slices = 4,194,304 f):
    float* convY  = ws;                                      // 2,097,152 f
    unsigned short* xTp = (unsigned short*)(ws + 2097152);   // 2,230,272 f
    // alive-through-pam region:
    float* ep     = ws + 4327424;                            // 4,194,304 f (64 slices)
    unsigned short* Wb2  = (unsigned short*)(ws + 8521728);  // 147,456 f
    unsigned short* Wqkv = (unsigned short*)(ws + 8669184);  // 10,240 f
    float* statsS  = ws + 8679424;                           // 128
    float* statsQ  = ws + 8679552;                           // 128
    float* biasAll = ws + 8679680;                           // 192 (pad)
    unsigned short* attnB = (unsigned short*)(ws + 8679872);  // 32,768 f
    unsigned short* qT    = (unsigned short*)(ws + 8712640);  // 131,072 f
    unsigned short* kT    = (unsigned short*)(ws + 8843712);  // 131,072 f
    unsigned short* vB    = (unsigned short*)(ws + 8974784);  // 1,048,576 f
    unsigned short* featB = (unsigned short*)(ws + 10023360); // 1,048,576 f
    unsigned short* fT    = (unsigned short*)(ws + 11071936); // 1,048,576 f -> 12,120,512 f
    // pamP bf16[4][4][128][4096] = 8,388,608 sh = 4,194,304 f, aliases
    // [0, 4,327,424) = convY+xTp (dead before pam; ep stays clear).
    unsigned short* pamP  = (unsigned short*)ws;

    prep_all_kernel<<<2257, 256, 0, stream>>>(x, conv_w, q_w, q_b, k_w, k_b,
                                              v_w, v_b, xTp, Wb2, Wqkv, biasAll,
                                              statsS, statsQ);
    conv_mfma_kernel<<<dim3(2, 64, 4), 256, 0, stream>>>(xTp, Wb2, convY, statsS, statsQ);
    bn_apply_kernel<<<dim3(2, 64, 4), 256, 0, stream>>>(convY, statsS, statsQ,
                                                        bn_g, bn_b, featB, fT);
    camqkv_kernel<<<512, 256, 0, stream>>>(featB, ep, Wqkv, biasAll, fT, qT, kT, vB);
    pam_attn_kernel<<<768, 256, 0, stream>>>(qT, kT, vB, pamP, ep, attnB);
    combine_kernel<<<dim3(64, 4), 256, 0, stream>>>(attnB, fT, featB, pamP, gca, gpa, out);
}

// Round 12
// 280.232 us; speedup vs baseline: 1.0023x; 1.0010x over previous
//
#include <hip/hip_runtime.h>
#include <math.h>

// Problem constants
#define BATCH 4
#define CIN   256
#define CCH   128      // Cout
#define HW    4096     // 64*64
#define CQK   16

using short8   = __attribute__((ext_vector_type(8))) short;
using floatx4  = __attribute__((ext_vector_type(4))) float;
using floatx16 = __attribute__((ext_vector_type(16))) float;
using uint4v   = __attribute__((ext_vector_type(4))) unsigned int;

// tanh via raw intrinsics: 1 v_mul + v_exp + v_add + v_rcp + v_fma.
// Saturates correctly: x->+inf => exp2->inf => rcp->0 => 1; x->-inf => -1.
__device__ __forceinline__ float fast_tanh(float x) {
    float e = __builtin_amdgcn_exp2f(x * 2.8853900817779268f);  // e^{2x}
    float r = __builtin_amdgcn_rcpf(e + 1.0f);
    return __builtin_fmaf(-2.0f, r, 1.0f);
}

__device__ __forceinline__ unsigned short f2bf(float f) {
    unsigned u = __float_as_uint(f);
    u += 0x7fff + ((u >> 16) & 1);   // RNE
    return (unsigned short)(u >> 16);
}

__device__ __forceinline__ float bf2f(unsigned short u) {
    return __uint_as_float(((unsigned)u) << 16);
}

// C/D row map for mfma_f32_32x32x16: row = (r&3) + 8*(r>>2) + 4*hi, col = lane&31
#define ROWMAP(r, hi) (((r) & 3) + (((r) >> 2) << 3) + ((hi) << 2))

#define XTP_ROW   (66 * 256)          // shorts per padded row
#define XTP_BATCH (66 * 66 * 256)     // shorts per batch

// ---------------------------------------------------------------------------
// 1) prep_all: [0,1024) x-transpose+halo; [1024,2176) conv weights;
//    [2176,2256) qkv weights; [2256] zero stats. grid 2257, block 256.
// ---------------------------------------------------------------------------
__global__ __launch_bounds__(256) void prep_all_kernel(
        const float* __restrict__ x, const float* __restrict__ w,
        const float* __restrict__ qw, const float* __restrict__ qb,
        const float* __restrict__ kw, const float* __restrict__ kb,
        const float* __restrict__ vw, const float* __restrict__ vb,
        unsigned short* __restrict__ xTp, unsigned short* __restrict__ Wb2,
        unsigned short* __restrict__ Wqkv, float* __restrict__ biasAll,
        float* __restrict__ statsS, float* __restrict__ statsQ) {
    const int bx = blockIdx.x, tid = threadIdx.x;
    if (bx < 1024) {
        __shared__ unsigned short lds[64][72];
        const int ci0 = (bx & 3) << 6, yr = (bx >> 2) & 63, b = bx >> 8;
        const int cir = tid >> 2, xc = tid & 3;
        const float* xp = x + (((b << 8) + ci0 + cir) << 12) + (yr << 6) + xc * 16;
#pragma unroll
        for (int j = 0; j < 4; ++j) {
            float4 v = *(const float4*)(xp + j * 4);
            int xi = xc * 16 + j * 4;
            lds[xi + 0][cir] = f2bf(v.x);
            lds[xi + 1][cir] = f2bf(v.y);
            lds[xi + 2][cir] = f2bf(v.z);
            lds[xi + 3][cir] = f2bf(v.w);
        }
        const short8 z8 = (short8){0,0,0,0,0,0,0,0};
        if (tid < 16) {
            int col = (tid >> 3) ? 65 : 0;
            int part = tid & 7;
            *(short8*)(xTp + b * XTP_BATCH + (yr + 1) * XTP_ROW + col * 256 +
                       ci0 + part * 8) = z8;
        }
        if (yr == 0 || yr == 63) {
            int row = (yr == 0) ? 0 : 65;
            for (int e = tid; e < 528; e += 256) {
                int xi = e >> 3, part = e & 7;
                *(short8*)(xTp + b * XTP_BATCH + row * XTP_ROW + xi * 256 +
                           ci0 + part * 8) = z8;
            }
        }
        __syncthreads();
        const int xr = tid >> 2, part = tid & 3;
        unsigned short* dst = xTp + b * XTP_BATCH + (yr + 1) * XTP_ROW +
                              (xr + 1) * 256 + ci0 + part * 16;
        *(short8*)(dst + 0) = *(const short8*)&lds[xr][part * 16 + 0];
        *(short8*)(dst + 8) = *(const short8*)&lds[xr][part * 16 + 8];
    } else if (bx < 2176) {
        int o = (bx - 1024) * 256 + tid;                 // < 294912
        int s   = o & 31;
        int co  = (o >> 5) & 127;
        int cc  = (o >> 12) & 7;
        int tap = o >> 15;
        int ci  = (cc << 5) + s;
        Wb2[o] = f2bf(w[co * 2304 + ci * 9 + tap]);
    } else if (bx < 2256) {
        int idx = (bx - 2176) * 256 + tid;               // < 20480
        int o = idx >> 7, c = idx & 127;
        float wv = (o < 16) ? qw[(o << 7) + c]
                 : (o < 32) ? kw[((o - 16) << 7) + c]
                            : vw[((o - 32) << 7) + c];
        Wqkv[idx] = f2bf(wv);
        if (idx < 160)
            biasAll[idx] = (idx < 16) ? qb[idx] : (idx < 32) ? kb[idx - 16] : vb[idx - 32];
    } else {
        if (tid < 128) { statsS[tid] = 0.f; statsQ[tid] = 0.f; }
    }
}

// ---------------------------------------------------------------------------
// 2) Conv implicit GEMM + fused BN-stat partials. LDS-free, barrier-free.
//    Wave = 32 co x 32 px. Software-pipelined at half-tap granularity:
//    double register buffers (16 frags each); step s issues ALL 16 loads of
//    step s+1 (no consumer in sight -> stays batched, pam-style), then runs
//    step s's 16 MFMAs. launch_bounds(256,2) gives the ~170-VGPR headroom
//    the R11 attempt lacked (R11 post-mortem: default bounds forced VGPR<=64
//    and the scheduler re-sank every load next to its consumer).
// grid(2, 64, 4) = 512 blocks -> 2 blocks/CU, block 256.
// ---------------------------------------------------------------------------
__global__ __launch_bounds__(256, 2) void conv_mfma_kernel(
        const unsigned short* __restrict__ xTp, const unsigned short* __restrict__ Wb2,
        float* __restrict__ y, float* __restrict__ statsS, float* __restrict__ statsQ) {
    const int tid = threadIdx.x;
    const int w = tid >> 6, lane = tid & 63, l15 = lane & 15, quad = lane >> 4;
    const int x0 = blockIdx.x << 5, yr = blockIdx.y, b = blockIdx.z;
    const int cobase = w << 5;

    floatx4 acc[2][2];
#pragma unroll
    for (int i = 0; i < 2; ++i)
#pragma unroll
        for (int j = 0; j < 2; ++j) acc[i][j] = (floatx4){0.f, 0.f, 0.f, 0.f};

    const unsigned short* xb = xTp + b * XTP_BATCH + yr * XTP_ROW;
    const int aco0 = cobase + l15;

    short8 A0[2][4], A1[2][4], B0[2][4], B1[2][4];

    auto load_half = [&](int buf, int s) {
        const int tap = s >> 1;
        const int ky  = tap / 3;
        const int kx  = tap - 3 * ky;
        const int cc0 = (s & 1) << 2;
        const unsigned short* arow = Wb2 + (tap << 15);
        const unsigned short* brow = xb + ky * XTP_ROW + (x0 + kx) * 256;
#pragma unroll
        for (int i = 0; i < 4; ++i) {
            const int cc = cc0 + i;
            B0[buf][i] = *(const short8*)(brow + (l15 << 8) + (cc << 5) + quad * 8);
            B1[buf][i] = *(const short8*)(brow + ((16 + l15) << 8) + (cc << 5) + quad * 8);
            A0[buf][i] = *(const short8*)(arow + (((cc << 7) + aco0) << 5) + quad * 8);
            A1[buf][i] = *(const short8*)(arow + (((cc << 7) + aco0 + 16) << 5) + quad * 8);
        }
    };

    load_half(0, 0);
#pragma unroll
    for (int s = 0; s < 18; ++s) {
        if (s < 17) load_half((s + 1) & 1, s + 1);
        const int cur = s & 1;
#pragma unroll
        for (int i = 0; i < 4; ++i) {
            acc[0][0] = __builtin_amdgcn_mfma_f32_16x16x32_bf16(A0[cur][i], B0[cur][i], acc[0][0], 0, 0, 0);
            acc[0][1] = __builtin_amdgcn_mfma_f32_16x16x32_bf16(A0[cur][i], B1[cur][i], acc[0][1], 0, 0, 0);
            acc[1][0] = __builtin_amdgcn_mfma_f32_16x16x32_bf16(A1[cur][i], B0[cur][i], acc[1][0], 0, 0, 0);
            acc[1][1] = __builtin_amdgcn_mfma_f32_16x16x32_bf16(A1[cur][i], B1[cur][i], acc[1][1], 0, 0, 0);
        }
    }

    // stores
#pragma unroll
    for (int ms = 0; ms < 2; ++ms)
#pragma unroll
        for (int ns = 0; ns < 2; ++ns) {
            int px = x0 + (ns << 4) + l15;
#pragma unroll
            for (int r = 0; r < 4; ++r) {
                int co = cobase + ms * 16 + quad * 4 + r;
                y[(((b << 7) + co) << 12) + (yr << 6) + px] = acc[ms][ns][r];
            }
        }
    // fused BN stat partials: reduce over the 16 px lanes, add both n-frags
#pragma unroll
    for (int ms = 0; ms < 2; ++ms)
#pragma unroll
        for (int r = 0; r < 4; ++r) {
            float s = acc[ms][0][r] + acc[ms][1][r];
            float q = acc[ms][0][r] * acc[ms][0][r] + acc[ms][1][r] * acc[ms][1][r];
#pragma unroll
            for (int off = 1; off < 16; off <<= 1) {
                s += __shfl_xor(s, off);
                q += __shfl_xor(q, off);
            }
            if (l15 == 0) {
                int co = cobase + ms * 16 + quad * 4 + r;
                atomicAdd(&statsS[co], s);
                atomicAdd(&statsQ[co], q);
            }
        }
}

// ---------------------------------------------------------------------------
// 3) BN apply + ReLU (scale computed inline from sums) -> featB + fT.
// grid(2, 64, 4), block 256
// ---------------------------------------------------------------------------
__global__ __launch_bounds__(256) void bn_apply_kernel(
        const float* __restrict__ y, const float* __restrict__ statsS,
        const float* __restrict__ statsQ, const float* __restrict__ gamma,
        const float* __restrict__ beta, unsigned short* __restrict__ featB,
        unsigned short* __restrict__ fT) {
    __shared__ unsigned short lds[64][72];
    const int tid = threadIdx.x;
    const int c0 = blockIdx.x * 64, n0 = blockIdx.y * 64, b = blockIdx.z;
    const int cir = tid >> 2, xc = tid & 3;
    const int c = c0 + cir;
    const float S = statsS[c], Q = statsQ[c];
    const float mean = S * (1.f / 16384.f);
    const float var  = Q * (1.f / 16384.f) - mean * mean;
    const float rstd = rsqrtf(var + 1e-5f);
    const float sc = gamma[c] * rstd;
    const float sh = beta[c] - mean * sc;
    const float* yp = y + (((b << 7) + c) << 12) + n0 + xc * 16;
    unsigned short* fp = featB + (((b << 7) + c) << 12) + n0 + xc * 16;
#pragma unroll
    for (int j = 0; j < 4; ++j) {
        float4 v = *(const float4*)(yp + j * 4);
        ushort4 o;
        o.x = f2bf(fmaxf(fmaf(v.x, sc, sh), 0.f));
        o.y = f2bf(fmaxf(fmaf(v.y, sc, sh), 0.f));
        o.z = f2bf(fmaxf(fmaf(v.z, sc, sh), 0.f));
        o.w = f2bf(fmaxf(fmaf(v.w, sc, sh), 0.f));
        *(ushort4*)(fp + j * 4) = o;
        int ni = xc * 16 + j * 4;
        lds[ni + 0][cir] = o.x;
        lds[ni + 1][cir] = o.y;
        lds[ni + 2][cir] = o.z;
        lds[ni + 3][cir] = o.w;
    }
    __syncthreads();
    const int nr = tid >> 2, part = tid & 3;
    unsigned short* dst = fT + (((b << 12) + n0 + nr) << 7) + c0 + part * 16;
    *(short8*)(dst + 0) = *(const short8*)&lds[nr][part * 16 + 0];
    *(short8*)(dst + 8) = *(const short8*)&lds[nr][part * 16 + 8];
}

// ---------------------------------------------------------------------------
// 4) Fused cam_energy (blocks [0,256)) + qkv (blocks [256,512)). grid 512.
// ---------------------------------------------------------------------------
__global__ __launch_bounds__(256) void camqkv_kernel(
        const unsigned short* __restrict__ featB, float* __restrict__ ep,
        const unsigned short* __restrict__ Wqkv, const float* __restrict__ biasAll,
        const unsigned short* __restrict__ fT,
        unsigned short* __restrict__ qT, unsigned short* __restrict__ kT,
        unsigned short* __restrict__ vB) {
    const int bx = blockIdx.x, tid = threadIdx.x;
    const int l31 = tid & 31, hi = (tid >> 5) & 1;
    if (bx < 256) {
        // cam_energy: split-K 64, kc = bx&63, b = bx>>6
        const int kc = bx & 63, b = bx >> 6, wv = tid >> 6;
        floatx16 acc[4];
#pragma unroll
        for (int t = 0; t < 4; ++t)
#pragma unroll
            for (int r = 0; r < 16; ++r) acc[t][r] = 0.f;
        for (int s = 0; s < 4; ++s) {
            const int k0 = (kc << 6) + (s << 4) + (hi << 3);
            short8 fr = *(const short8*)&featB[(((b << 7) + (wv << 5) + l31) << 12) + k0];
            short8 fc0 = *(const short8*)&featB[(((b << 7) +  0 + l31) << 12) + k0];
            short8 fc1 = *(const short8*)&featB[(((b << 7) + 32 + l31) << 12) + k0];
            short8 fc2 = *(const short8*)&featB[(((b << 7) + 64 + l31) << 12) + k0];
            short8 fc3 = *(const short8*)&featB[(((b << 7) + 96 + l31) << 12) + k0];
            acc[0] = __builtin_amdgcn_mfma_f32_32x32x16_bf16(fr, fc0, acc[0], 0, 0, 0);
            acc[1] = __builtin_amdgcn_mfma_f32_32x32x16_bf16(fr, fc1, acc[1], 0, 0, 0);
            acc[2] = __builtin_amdgcn_mfma_f32_32x32x16_bf16(fr, fc2, acc[2], 0, 0, 0);
            acc[3] = __builtin_amdgcn_mfma_f32_32x32x16_bf16(fr, fc3, acc[3], 0, 0, 0);
        }
#pragma unroll
        for (int t = 0; t < 4; ++t)
#pragma unroll
            for (int r = 0; r < 16; ++r) {
                int c = ((tid >> 6) << 5) + ROWMAP(r, hi);
                int d = (t << 5) + l31;
                ep[(((kc << 2) + b) << 14) + (c << 7) + d] = acc[t][r];
            }
    } else {
        // qkv: bi = bx-256; ntile = bi&63, b = bi>>6
        const int bi = bx - 256, b = bi >> 6, w = tid >> 6;
        const int n0 = ((bi & 63) << 6) + ((w >> 1) << 5);
        const int tstart = (w & 1) ? 3 : 0;
        const int tcnt   = (w & 1) ? 2 : 3;
        floatx16 acc[3];
#pragma unroll
        for (int t = 0; t < 3; ++t)
#pragma unroll
            for (int r = 0; r < 16; ++r) acc[t][r] = 0.f;
        for (int s = 0; s < 8; ++s) {
            const int k0 = (s << 4) + (hi << 3);
            short8 bf = *(const short8*)&fT[(((b << 12) + n0 + l31) << 7) + k0];
#pragma unroll
            for (int ti = 0; ti < 3; ++ti) {
                if (ti < tcnt) {
                    short8 aw = *(const short8*)&Wqkv[((((tstart + ti) << 5) + l31) << 7) + k0];
                    acc[ti] = __builtin_amdgcn_mfma_f32_32x32x16_bf16(aw, bf, acc[ti], 0, 0, 0);
                }
            }
        }
        const int n = n0 + l31;
#pragma unroll
        for (int ti = 0; ti < 3; ++ti) {
            if (ti >= tcnt) continue;
            const int t = tstart + ti;
#pragma unroll
            for (int r = 0; r < 16; ++r) {
                int o = (t << 5) + ROWMAP(r, hi);
                float val = acc[ti][r] + biasAll[o];
                if (t == 0) {
                    if (o < 16) qT[(((b << 12) + n) << 4) + o] = f2bf(val);
                    else        kT[(((b << 12) + n) << 4) + o - 16] = f2bf(val);
                } else if (o >= 32) {
                    vB[(((b << 7) + o - 32) << 12) + n] = f2bf(val);
                }
            }
        }
    }
}

// ---------------------------------------------------------------------------
// 5) Fused pam (blocks [0,512)) + cam_attn (blocks [512,768)). grid 768.
//    pam: wave-autonomous, 4-way n-split, shfl hi-half swap, fast tanh.
// ---------------------------------------------------------------------------
__global__ __launch_bounds__(256) void pam_attn_kernel(
        const unsigned short* __restrict__ qT, const unsigned short* __restrict__ kT,
        const unsigned short* __restrict__ vB, unsigned short* __restrict__ pamP,
        const float* __restrict__ ep, unsigned short* __restrict__ attnB) {
    const int bx = blockIdx.x, tid = threadIdx.x;
    if (bx < 512) {
        const int nh = bx & 3, b = bx >> 7;
        const int w = tid >> 6, lane = tid & 63, l31 = lane & 31, hi = lane >> 5;
        const int m0 = (((bx >> 2) & 31) << 7) + (w << 5);

        short8 bq = *(const short8*)&qT[(((b << 12) + m0 + l31) << 4) + hi * 8];

        floatx16 acc[4], zero16;
#pragma unroll
        for (int r = 0; r < 16; ++r) {
            acc[0][r] = 0.f; acc[1][r] = 0.f; acc[2][r] = 0.f; acc[3][r] = 0.f;
            zero16[r] = 0.f;
        }

        const int nbase = nh << 10;
        short8 ak = *(const short8*)&kT[(((b << 12) + nbase + l31) << 4) + hi * 8];

        for (int nc = 0; nc < 32; ++nc) {
            const int na = nbase + (nc << 5);
            short8 av[8];
#pragma unroll
            for (int ct = 0; ct < 4; ++ct) {
                const unsigned short* vp = vB + (((b << 7) + (ct << 5) + l31) << 12) + na + hi * 8;
                av[2 * ct]     = *(const short8*)(vp);
                av[2 * ct + 1] = *(const short8*)(vp + 16);
            }
            floatx16 s = __builtin_amdgcn_mfma_f32_32x32x16_bf16(ak, bq, zero16, 0, 0, 0);
            if (nc < 31)
                ak = *(const short8*)&kT[(((b << 12) + na + 32 + l31) << 4) + hi * 8];
            unsigned p[8];
#pragma unroll
            for (int i = 0; i < 8; ++i) {
                float t0 = fast_tanh(s[2 * i]);
                float t1 = fast_tanh(s[2 * i + 1]);
                p[i] = (__float_as_uint(t1) & 0xFFFF0000u) | (__float_as_uint(t0) >> 16);
            }
            unsigned sh[8];
#pragma unroll
            for (int i = 0; i < 8; ++i) sh[i] = __shfl_xor(p[i], 32, 64);
            uint4v b1u, b2u;
            b1u[0] = hi ? sh[2] : p[0];
            b1u[1] = hi ? sh[3] : p[1];
            b1u[2] = hi ? p[2] : sh[0];
            b1u[3] = hi ? p[3] : sh[1];
            b2u[0] = hi ? sh[6] : p[4];
            b2u[1] = hi ? sh[7] : p[5];
            b2u[2] = hi ? p[6] : sh[4];
            b2u[3] = hi ? p[7] : sh[5];
            short8 B1 = __builtin_bit_cast(short8, b1u);
            short8 B2 = __builtin_bit_cast(short8, b2u);
#pragma unroll
            for (int ct = 0; ct < 4; ++ct) {
                acc[ct] = __builtin_amdgcn_mfma_f32_32x32x16_bf16(av[2 * ct], B1, acc[ct], 0, 0, 0);
                acc[ct] = __builtin_amdgcn_mfma_f32_32x32x16_bf16(av[2 * ct + 1], B2, acc[ct], 0, 0, 0);
            }
        }
        const int pbase = (((nh << 2) + b) << 19) + m0 + l31;
#pragma unroll
        for (int ct = 0; ct < 4; ++ct)
#pragma unroll
            for (int r = 0; r < 16; ++r) {
                int c = (ct << 5) + ROWMAP(r, hi);
                pamP[pbase + (c << 12)] = f2bf(acc[ct][r]);
            }
    } else {
        // cam_attn: bi = bx-512 (0..255): b = bi>>6, 2 rows per block
        const int bi = bx - 512, b = bi >> 6;
        const int half = tid >> 7, t = tid & 127;
        const int c = ((bi & 63) << 1) + half;
        float v = 0.f;
#pragma unroll 8
        for (int s = 0; s < 64; ++s)
            v += ep[(((s << 2) + b) << 14) + (c << 7) + t];
        float m = v;
        for (int off = 32; off; off >>= 1) m = fmaxf(m, __shfl_down(m, off));
        __shared__ float mx[4];
        if ((tid & 63) == 0) mx[tid >> 6] = m;
        __syncthreads();
        float M = fmaxf(mx[half << 1], mx[(half << 1) + 1]);
        attnB[(b << 14) + (c << 7) + t] = f2bf(fast_tanh(M - v));
    }
}

// ---------------------------------------------------------------------------
// 6) Combine: out = 3*feat + g_ca*(attn @ f) + g_pa*(sum_4 pamP).
// grid(64, 4), block 256.
// ---------------------------------------------------------------------------
__global__ __launch_bounds__(256) void combine_kernel(
        const unsigned short* __restrict__ attnB, const unsigned short* __restrict__ fT,
        const unsigned short* __restrict__ featB, const unsigned short* __restrict__ pamP,
        const float* __restrict__ gca, const float* __restrict__ gpa,
        float* __restrict__ out) {
    const int b = blockIdx.y, tid = threadIdx.x;
    const int w = tid >> 6, l31 = tid & 31, hi = (tid >> 5) & 1;
    const int m0 = (blockIdx.x << 6) + ((w >> 1) << 5);
    const int ct0 = (w & 1) << 1;
    floatx16 acc[2];
#pragma unroll
    for (int t = 0; t < 2; ++t)
#pragma unroll
        for (int r = 0; r < 16; ++r) acc[t][r] = 0.f;

    for (int s = 0; s < 8; ++s) {
        const int k0 = (s << 4) + (hi << 3);
        short8 bf = *(const short8*)&fT[(((b << 12) + m0 + l31) << 7) + k0];
        short8 a0 = *(const short8*)&attnB[(b << 14) + ((((ct0 + 0) << 5) + l31) << 7) + k0];
        short8 a1 = *(const short8*)&attnB[(b << 14) + ((((ct0 + 1) << 5) + l31) << 7) + k0];
        acc[0] = __builtin_amdgcn_mfma_f32_32x32x16_bf16(a0, bf, acc[0], 0, 0, 0);
        acc[1] = __builtin_amdgcn_mfma_f32_32x32x16_bf16(a1, bf, acc[1], 0, 0, 0);
    }
    const float gc = gca[0], gp = gpa[0];
    const int m = m0 + l31;
#pragma unroll
    for (int t = 0; t < 2; ++t)
#pragma unroll
        for (int r = 0; r < 16; ++r) {
            int c = ((ct0 + t) << 5) + ROWMAP(r, hi);
            int ci = (c << 12) + m;
            float p = bf2f(pamP[((0 * 4 + b) << 19) + ci]) +
                      bf2f(pamP[((1 * 4 + b) << 19) + ci]) +
                      bf2f(pamP[((2 * 4 + b) << 19) + ci]) +
                      bf2f(pamP[((3 * 4 + b) << 19) + ci]);
            float fb = bf2f(featB[(((b << 7) + c) << 12) + m]);
            out[(((b << 7) + c) << 12) + m] = 3.f * fb + gc * acc[t][r] + gp * p;
        }
}

// ---------------------------------------------------------------------------
extern "C" void kernel_launch(void* const* d_in, const int* in_sizes, int n_in,
                              void* d_out, int out_size, void* d_ws, size_t ws_size,
                              hipStream_t stream) {
    const float* x      = (const float*)d_in[0];
    const float* conv_w = (const float*)d_in[1];
    const float* bn_g   = (const float*)d_in[2];
    const float* bn_b   = (const float*)d_in[3];
    const float* q_w    = (const float*)d_in[4];
    const float* q_b    = (const float*)d_in[5];
    const float* k_w    = (const float*)d_in[6];
    const float* k_b    = (const float*)d_in[7];
    const float* v_w    = (const float*)d_in[8];
    const float* v_b    = (const float*)d_in[9];
    const float* gca    = (const float*)d_in[10];
    const float* gpa    = (const float*)d_in[11];
    float* out = (float*)d_out;

    float* ws = (float*)d_ws;
    // dead-by-pam region (aliased by pamP, 4 slices = 4,194,304 f):
    float* convY  = ws;                                      // 2,097,152 f
    unsigned short* xTp = (unsigned short*)(ws + 2097152);   // 2,230,272 f
    // alive-through-pam region:
    float* ep     = ws + 4327424;                            // 4,194,304 f (64 slices)
    unsigned short* Wb2  = (unsigned short*)(ws + 8521728);  // 147,456 f
    unsigned short* Wqkv = (unsigned short*)(ws + 8669184);  // 10,240 f
    float* statsS  = ws + 8679424;                           // 128
    float* statsQ  = ws + 8679552;                           // 128
    float* biasAll = ws + 8679680;                           // 192 (pad)
    unsigned short* attnB = (unsigned short*)(ws + 8679872);  // 32,768 f
    unsigned short* qT    = (unsigned short*)(ws + 8712640);  // 131,072 f
    unsigned short* kT    = (unsigned short*)(ws + 8843712);  // 131,072 f
    unsigned short* vB    = (unsigned short*)(ws + 8974784);  // 1,048,576 f
    unsigned short* featB = (unsigned short*)(ws + 10023360); // 1,048,576 f
    unsigned short* fT    = (unsigned short*)(ws + 11071936); // 1,048,576 f -> 12,120,512 f
    // pamP bf16[4][4][128][4096] = 8,388,608 sh = 4,194,304 f, aliases
    // [0, 4,327,424) = convY+xTp (dead before pam; ep stays clear).
    unsigned short* pamP  = (unsigned short*)ws;

    prep_all_kernel<<<2257, 256, 0, stream>>>(x, conv_w, q_w, q_b, k_w, k_b,
                                              v_w, v_b, xTp, Wb2, Wqkv, biasAll,
                                              statsS, statsQ);
    conv_mfma_kernel<<<dim3(2, 64, 4), 256, 0, stream>>>(xTp, Wb2, convY, statsS, statsQ);
    bn_apply_kernel<<<dim3(2, 64, 4), 256, 0, stream>>>(convY, statsS, statsQ,
                                                        bn_g, bn_b, featB, fT);
    camqkv_kernel<<<512, 256, 0, stream>>>(featB, ep, Wqkv, biasAll, fT, qT, kT, vB);
    pam_attn_kernel<<<768, 256, 0, stream>>>(qT, kT, vB, pamP, ep, attnB);
    combine_kernel<<<dim3(64, 4), 256, 0, stream>>>(attnB, fT, featB, pamP, gca, gpa, out);
}